// Round 1
// baseline (532.958 us; speedup 1.0000x reference)
//
#include <hip/hip_runtime.h>

constexpr int kB = 8, kN = 8192, kS = 2048;
constexpr int kD1 = 128, kD2 = 256, kCin = 384, kM0 = 256, kM1 = 128;
constexpr float kEps = 1e-5f;

typedef float f32x4 __attribute__((ext_vector_type(4)));

// ---------------- Kernel 1: 3-NN + inverse-distance interpolation ----------
// One thread per query point; xyz2 staged in LDS as fp64 (48 KB).
// fp64 distances so the top-3 ordering matches the (f64) numpy reference;
// strict '<' keeps lowest index first on ties, matching lax.top_k.
__global__ __launch_bounds__(256) void knn_interp_kernel(
    const float* __restrict__ xyz1, const float* __restrict__ xyz2,
    const float* __restrict__ points2, float* __restrict__ interp)
{
    __shared__ double sx[kS], sy[kS], sz[kS];
    const int b = blockIdx.x >> 5;           // 32 blocks per batch
    const int n0 = (blockIdx.x & 31) << 8;   // 256 points per block
    const int t = threadIdx.x;
    const float* x2 = xyz2 + b * 3 * kS;
    for (int s = t; s < kS; s += 256) {
        sx[s] = (double)x2[s];
        sy[s] = (double)x2[kS + s];
        sz[s] = (double)x2[2 * kS + s];
    }
    __syncthreads();
    const int n = n0 + t;
    const float* x1 = xyz1 + b * 3 * kN;
    const double px = (double)x1[n], py = (double)x1[kN + n], pz = (double)x1[2 * kN + n];
    double d0 = 1e300, d1 = 1e300, d2 = 1e300;
    int i0 = 0, i1 = 0, i2 = 0;
    for (int s = 0; s < kS; ++s) {
        double ex = px - sx[s], ey = py - sy[s], ez = pz - sz[s];
        double d = ex * ex + ey * ey + ez * ez;
        if (d < d2) {
            if (d < d1) {
                if (d < d0) { d2 = d1; i2 = i1; d1 = d0; i1 = i0; d0 = d; i0 = s; }
                else        { d2 = d1; i2 = i1; d1 = d;  i1 = s; }
            } else          { d2 = d;  i2 = s; }
        }
    }
    const double r0 = 1.0 / (d0 + 1e-8), r1 = 1.0 / (d1 + 1e-8), r2 = 1.0 / (d2 + 1e-8);
    const double rs = 1.0 / (r0 + r1 + r2);
    const float w0 = (float)(r0 * rs), w1 = (float)(r1 * rs), w2 = (float)(r2 * rs);
    const float* p2 = points2 + b * kD2 * kS;
    float* op = interp + b * kD2 * kN + n;
    // per-d writes are coalesced across the 256 threads (consecutive n)
    for (int d = 0; d < kD2; ++d) {
        const float* row = p2 + d * kS;   // 8 KB row, L1/L2 resident (2 MB/batch)
        op[d * kN] = w0 * row[i0] + w1 * row[i1] + w2 * row[i2];
    }
}

// ---------------- Fused GEMM (+optional BN-ReLU on load) + BN-stats --------
// fp32 baseline: 128(o) x 128(n) tile, 256 threads, 8x8 per thread, K-chunk 32.
// CONCAT: input = [interp(256); points1(128)].  BNRELU: apply per-channel
// scale/shift + relu while staging the K operand.
// Epilogue: raw Y store + per-channel sum/sumsq (shuffle-reduce + atomics).
template <int K, int MTOT, bool CONCAT, bool BNRELU>
__global__ __launch_bounds__(256) void gemm_bn_kernel(
    const float* __restrict__ W, const float* __restrict__ Xa,
    const float* __restrict__ Xb, const float* __restrict__ scale,
    const float* __restrict__ shift, float* __restrict__ Y,
    float* __restrict__ gsum, float* __restrict__ gsq)
{
    constexpr int TO = 128, TN = 128, TK = 32;
    __shared__ float Wt[TK][TO + 4];   // +4 pad: conflict-free b128 reads
    __shared__ float Xt[TK][TN];
    __shared__ float ssum[TO], ssq[TO];
    const int t = threadIdx.x;
    const int tx = t & 15, ty = t >> 4;
    const int bn = blockIdx.x * TN;
    const int bo = blockIdx.y * TO;
    const int b = blockIdx.z;

    float acc[8][8];
#pragma unroll
    for (int i = 0; i < 8; ++i)
#pragma unroll
        for (int j = 0; j < 8; ++j) acc[i][j] = 0.f;

    const int kk = t & 31, wo = t >> 5;    // W staging: coalesced in k
    const int xn = t & 127, xc = t >> 7;   // X staging: coalesced in n

    for (int k0 = 0; k0 < K; k0 += TK) {
#pragma unroll
        for (int p = 0; p < TO / 8; ++p) {
            int o = wo + p * 8;
            Wt[kk][o] = W[(bo + o) * K + k0 + kk];
        }
#pragma unroll
        for (int p = 0; p < TK / 2; ++p) {
            int c = k0 + xc + p * 2;
            float v;
            if constexpr (CONCAT) {
                v = (c < kD2) ? Xa[(b * kD2 + c) * kN + bn + xn]
                              : Xb[(b * kD1 + (c - kD2)) * kN + bn + xn];
            } else {
                v = Xa[(b * K + c) * kN + bn + xn];
                if constexpr (BNRELU) v = fmaxf(fmaf(v, scale[c], shift[c]), 0.f);
            }
            Xt[xc + p * 2][xn] = v;
        }
        __syncthreads();
#pragma unroll 8
        for (int k = 0; k < TK; ++k) {
            f32x4 A0 = *(const f32x4*)&Wt[k][ty * 8];
            f32x4 A1 = *(const f32x4*)&Wt[k][ty * 8 + 4];
            f32x4 B0 = *(const f32x4*)&Xt[k][tx * 8];
            f32x4 B1 = *(const f32x4*)&Xt[k][tx * 8 + 4];
            float a[8] = {A0[0], A0[1], A0[2], A0[3], A1[0], A1[1], A1[2], A1[3]};
            float bv[8] = {B0[0], B0[1], B0[2], B0[3], B1[0], B1[1], B1[2], B1[3]};
#pragma unroll
            for (int i = 0; i < 8; ++i)
#pragma unroll
                for (int j = 0; j < 8; ++j)
                    acc[i][j] = fmaf(a[i], bv[j], acc[i][j]);
        }
        __syncthreads();
    }

    // conv bias is skipped everywhere: BN's mean subtraction cancels it exactly.
    float* yb = Y + (b * MTOT + bo) * kN;
#pragma unroll
    for (int i = 0; i < 8; ++i) {
        const int ol = ty * 8 + i;
        float ps = 0.f, pq = 0.f;
#pragma unroll
        for (int j = 0; j < 8; ++j) { float v = acc[i][j]; ps += v; pq += v * v; }
#pragma unroll
        for (int off = 1; off < 16; off <<= 1) {   // reduce across the 16 tx lanes
            ps += __shfl_xor(ps, off);
            pq += __shfl_xor(pq, off);
        }
        if (tx == 0) { ssum[ol] = ps; ssq[ol] = pq; }
        f32x4 v0 = {acc[i][0], acc[i][1], acc[i][2], acc[i][3]};
        f32x4 v1 = {acc[i][4], acc[i][5], acc[i][6], acc[i][7]};
        f32x4* dst = (f32x4*)(yb + ol * kN + bn + tx * 8);
        dst[0] = v0; dst[1] = v1;
    }
    __syncthreads();
    if (t < TO) {
        atomicAdd(&gsum[bo + t], ssum[t]);
        atomicAdd(&gsq[bo + t], ssq[t]);
    }
}

// ---------------- BN stat finalize: scale/shift per channel ----------------
__global__ void bn_finalize_kernel(const float* __restrict__ gsum, const float* __restrict__ gsq,
                                   const float* __restrict__ g, const float* __restrict__ be,
                                   float* __restrict__ scale, float* __restrict__ shift, int M)
{
    int t = threadIdx.x;
    if (t < M) {
        const float invn = 1.0f / 65536.0f;   // B*N samples per channel
        float mean = gsum[t] * invn;
        float var = gsq[t] * invn - mean * mean;   // biased var (jnp.var default)
        float sc = g[t] * rsqrtf(var + kEps);
        scale[t] = sc;
        shift[t] = fmaf(-mean, sc, be[t]);
    }
}

// ---------------- Final in-place BN+ReLU on d_out --------------------------
__global__ __launch_bounds__(256) void bn_relu_out_kernel(
    float* __restrict__ out, const float* __restrict__ scale, const float* __restrict__ shift)
{
    const int total = kB * kM1 * kN / 4;
    for (int idx = blockIdx.x * blockDim.x + threadIdx.x; idx < total;
         idx += gridDim.x * blockDim.x) {
        const int p = (idx >> 11) & 127;   // channel = (idx*4 / 8192) % 128
        const float sc = scale[p], sh = shift[p];
        f32x4 v = ((f32x4*)out)[idx];
#pragma unroll
        for (int j = 0; j < 4; ++j) v[j] = fmaxf(fmaf(v[j], sc, sh), 0.f);
        ((f32x4*)out)[idx] = v;
    }
}

extern "C" void kernel_launch(void* const* d_in, const int* in_sizes, int n_in,
                              void* d_out, int out_size, void* d_ws, size_t ws_size,
                              hipStream_t stream)
{
    const float* xyz1    = (const float*)d_in[0];
    const float* xyz2    = (const float*)d_in[1];
    const float* points1 = (const float*)d_in[2];
    const float* points2 = (const float*)d_in[3];
    const float* w0      = (const float*)d_in[4];
    // d_in[5] = b0, d_in[9] = b1: conv biases cancel in BatchNorm -> unused
    const float* g0      = (const float*)d_in[6];
    const float* be0     = (const float*)d_in[7];
    const float* w1      = (const float*)d_in[8];
    const float* g1      = (const float*)d_in[10];
    const float* be1     = (const float*)d_in[11];
    float* out = (float*)d_out;

    char* ws = (char*)d_ws;
    float* interp = (float*)ws;                                   // 64 MiB
    float* y0     = (float*)(ws + (size_t)64 * 1024 * 1024);      // 64 MiB
    float* stats  = (float*)(ws + (size_t)128 * 1024 * 1024);     // ~6 KB
    float* sum0 = stats,         *sq0 = stats + 256;
    float* sum1 = stats + 512,   *sq1 = stats + 640;
    float* scale0 = stats + 768, *shift0 = stats + 1024;
    float* scale1 = stats + 1280, *shift1 = stats + 1408;

    hipMemsetAsync(stats, 0, 768 * sizeof(float), stream);
    knn_interp_kernel<<<256, 256, 0, stream>>>(xyz1, xyz2, points2, interp);
    gemm_bn_kernel<kCin, kM0, true, false><<<dim3(64, 2, 8), 256, 0, stream>>>(
        w0, interp, points1, nullptr, nullptr, y0, sum0, sq0);
    bn_finalize_kernel<<<1, 256, 0, stream>>>(sum0, sq0, g0, be0, scale0, shift0, 256);
    gemm_bn_kernel<kM0, kM1, false, true><<<dim3(64, 1, 8), 256, 0, stream>>>(
        w1, y0, nullptr, scale0, shift0, out, sum1, sq1);
    bn_finalize_kernel<<<1, 128, 0, stream>>>(sum1, sq1, g1, be1, scale1, shift1, 128);
    bn_relu_out_kernel<<<4096, 256, 0, stream>>>(out, scale1, shift1);
}